// Round 1
// baseline (1274.948 us; speedup 1.0000x reference)
//
#include <hip/hip_runtime.h>
#include <cstddef>

// Problem constants: B=2, S=2048, D=1024, H=16, DH=64, M=B*S=4096
//
// Pipeline:
//   q2  = perm2(queries @ Wq^T + bq)   (double split_proj folded into store)
//   kb  = perm1(keys    @ Wk^T + bk)   (split_proj folded into store)
//   vb  = perm1(values  @ Wv^T + bv)
//   ctx = attention(q2, kb, vb, mask)  (flash-style, online softmax)
//   out = ctx @ Wo^T + bo
//
// perm1: dst[((b*16+h)*2048 + s)*64 + dh]            <- src[b, s, h*64+dh]
// perm2: dst[((b*16+(s&15))*2048 + h*128+(s>>4))*64 + dh]  (since 2048%16==0)

// ---------------- GEMM: C = A @ W^T + bias, 128x128x16 tiles, 8x8 micro ----
// A: (M,1024) row-major; W: (1024,1024) row-major (so C[m,n] = sum_k A[m,k]*W[n,k])
template <int MODE>
__global__ __launch_bounds__(256)
void gemm_wt(const float* __restrict__ A, const float* __restrict__ W,
             const float* __restrict__ bias, float* __restrict__ C)
{
    constexpr int BK  = 16;
    constexpr int LDT = 132;                 // 128 + 4 pad, rows stay 16B-aligned
    __shared__ float AsT[BK][LDT];           // [k][m]
    __shared__ float WsT[BK][LDT];           // [k][n]

    const int t  = threadIdx.x;
    const int tx = t & 15;
    const int ty = t >> 4;
    const int m0 = blockIdx.y * 128;
    const int n0 = blockIdx.x * 128;

    const int srow = t >> 2;                 // 0..63
    const int sc   = (t & 3) << 2;           // 0,4,8,12

    float acc[8][8] = {};

    for (int k0 = 0; k0 < 1024; k0 += BK) {
        __syncthreads();
        const float4 a0 = *(const float4*)&A[(size_t)(m0 + srow)      * 1024 + k0 + sc];
        const float4 a1 = *(const float4*)&A[(size_t)(m0 + srow + 64) * 1024 + k0 + sc];
        const float4 w0 = *(const float4*)&W[(size_t)(n0 + srow)      * 1024 + k0 + sc];
        const float4 w1 = *(const float4*)&W[(size_t)(n0 + srow + 64) * 1024 + k0 + sc];
        AsT[sc+0][srow]    = a0.x; AsT[sc+1][srow]    = a0.y; AsT[sc+2][srow]    = a0.z; AsT[sc+3][srow]    = a0.w;
        AsT[sc+0][srow+64] = a1.x; AsT[sc+1][srow+64] = a1.y; AsT[sc+2][srow+64] = a1.z; AsT[sc+3][srow+64] = a1.w;
        WsT[sc+0][srow]    = w0.x; WsT[sc+1][srow]    = w0.y; WsT[sc+2][srow]    = w0.z; WsT[sc+3][srow]    = w0.w;
        WsT[sc+0][srow+64] = w1.x; WsT[sc+1][srow+64] = w1.y; WsT[sc+2][srow+64] = w1.z; WsT[sc+3][srow+64] = w1.w;
        __syncthreads();
        #pragma unroll
        for (int kk = 0; kk < BK; ++kk) {
            float xa[8], yb[8];
            *(float4*)&xa[0] = *(const float4*)&AsT[kk][ty*8];
            *(float4*)&xa[4] = *(const float4*)&AsT[kk][ty*8+4];
            *(float4*)&yb[0] = *(const float4*)&WsT[kk][tx*8];
            *(float4*)&yb[4] = *(const float4*)&WsT[kk][tx*8+4];
            #pragma unroll
            for (int i = 0; i < 8; ++i)
                #pragma unroll
                for (int j = 0; j < 8; ++j)
                    acc[i][j] += xa[i] * yb[j];
        }
    }

    #pragma unroll
    for (int i = 0; i < 8; ++i) {
        const int m  = m0 + ty*8 + i;
        const int bb = m >> 11;              // batch
        const int s  = m & 2047;             // sequence pos
        #pragma unroll
        for (int j4 = 0; j4 < 2; ++j4) {
            const int n = n0 + tx*8 + j4*4;
            const float4 bvv = *(const float4*)&bias[n];
            float4 r;
            r.x = acc[i][j4*4+0] + bvv.x;
            r.y = acc[i][j4*4+1] + bvv.y;
            r.z = acc[i][j4*4+2] + bvv.z;
            r.w = acc[i][j4*4+3] + bvv.w;
            size_t dst;
            if (MODE == 0) {
                dst = (size_t)m * 1024 + n;
            } else {
                const int h  = n >> 6;
                const int dh = n & 63;       // multiple of 4 -> float4 store ok
                if (MODE == 1) {
                    dst = ((size_t)(bb*16 + h) * 2048 + s) * 64 + dh;
                } else {                     // MODE 2: double split_proj
                    const int h2 = s & 15;
                    const int s2 = h*128 + (s >> 4);
                    dst = ((size_t)(bb*16 + h2) * 2048 + s2) * 64 + dh;
                }
            }
            *(float4*)&C[dst] = r;
        }
    }
}

// ---------------- Flash-style attention, fp32 --------------------------------
// One block: 64 queries of one (b,h). 256 threads as 16x16, 4x4 micro-tiles.
// scores = (Q*0.125) @ K^T + mask*(-1e9); online softmax; acc = P @ V.
__global__ __launch_bounds__(256)
void attn_fwd(const float* __restrict__ Q2, const float* __restrict__ Kb,
              const float* __restrict__ Vb, const int* __restrict__ mask,
              float* __restrict__ ctx)
{
    constexpr int LD = 68;
    __shared__ float QsT[64][LD];            // [d][q], pre-scaled by 0.125
    __shared__ float KsT[64][LD];            // [d][k]
    __shared__ float Vs [64][LD];            // [k][d]
    __shared__ float PsT[64][LD];            // [k][q]

    const int t  = threadIdx.x;
    const int tx = t & 15;
    const int ty = t >> 4;
    const int q0 = blockIdx.x * 64;
    const int bh = blockIdx.y;               // b*16 + h
    const size_t hoff = (size_t)bh * (2048*64);
    const float* qh = Q2 + hoff;
    const float* kh = Kb + hoff;
    const float* vh = Vb + hoff;

    #pragma unroll
    for (int r = 0; r < 4; ++r) {            // stage Q^T once, scaled
        const int f   = t + 256*r;
        const int row = f >> 4;
        const int c   = (f & 15) << 2;
        const float4 v = *(const float4*)&qh[(size_t)(q0+row)*64 + c];
        QsT[c+0][row] = v.x * 0.125f;
        QsT[c+1][row] = v.y * 0.125f;
        QsT[c+2][row] = v.z * 0.125f;
        QsT[c+3][row] = v.w * 0.125f;
    }

    float m_r[4], l_r[4], acc[4][4];
    #pragma unroll
    for (int i = 0; i < 4; ++i) {
        m_r[i] = -1e30f; l_r[i] = 0.f;
        #pragma unroll
        for (int j = 0; j < 4; ++j) acc[i][j] = 0.f;
    }

    for (int kt = 0; kt < 32; ++kt) {
        const int k0 = kt * 64;
        __syncthreads();                     // WAR: prev PV reads / first-iter QsT
        #pragma unroll
        for (int r = 0; r < 4; ++r) {        // stage K^T and V
            const int f   = t + 256*r;
            const int row = f >> 4;
            const int c   = (f & 15) << 2;
            const float4 kv = *(const float4*)&kh[(size_t)(k0+row)*64 + c];
            KsT[c+0][row] = kv.x;
            KsT[c+1][row] = kv.y;
            KsT[c+2][row] = kv.z;
            KsT[c+3][row] = kv.w;
            *(float4*)&Vs[row][c] = *(const float4*)&vh[(size_t)(k0+row)*64 + c];
        }
        __syncthreads();

        float sc_t[4][4] = {};
        #pragma unroll
        for (int d = 0; d < 64; ++d) {       // Q K^T (scale folded into Q)
            float qa[4], kk4[4];
            *(float4*)&qa[0]  = *(const float4*)&QsT[d][ty*4];
            *(float4*)&kk4[0] = *(const float4*)&KsT[d][tx*4];
            #pragma unroll
            for (int i = 0; i < 4; ++i)
                #pragma unroll
                for (int j = 0; j < 4; ++j)
                    sc_t[i][j] += qa[i] * kk4[j];
        }
        #pragma unroll
        for (int i = 0; i < 4; ++i) {        // additive mask
            const int4 mi = *(const int4*)&mask[(size_t)(q0 + ty*4 + i)*2048 + k0 + tx*4];
            sc_t[i][0] += (float)mi.x * -1e9f;
            sc_t[i][1] += (float)mi.y * -1e9f;
            sc_t[i][2] += (float)mi.z * -1e9f;
            sc_t[i][3] += (float)mi.w * -1e9f;
        }
        #pragma unroll
        for (int i = 0; i < 4; ++i) {        // online softmax (16-lane row groups)
            float rm = fmaxf(fmaxf(sc_t[i][0], sc_t[i][1]), fmaxf(sc_t[i][2], sc_t[i][3]));
            rm = fmaxf(rm, __shfl_xor(rm, 1));
            rm = fmaxf(rm, __shfl_xor(rm, 2));
            rm = fmaxf(rm, __shfl_xor(rm, 4));
            rm = fmaxf(rm, __shfl_xor(rm, 8));
            const float mn    = fmaxf(m_r[i], rm);
            const float scale = __expf(m_r[i] - mn);
            const float p0 = __expf(sc_t[i][0] - mn);
            const float p1 = __expf(sc_t[i][1] - mn);
            const float p2 = __expf(sc_t[i][2] - mn);
            const float p3 = __expf(sc_t[i][3] - mn);
            float ps = p0 + p1 + p2 + p3;
            ps += __shfl_xor(ps, 1);
            ps += __shfl_xor(ps, 2);
            ps += __shfl_xor(ps, 4);
            ps += __shfl_xor(ps, 8);
            l_r[i] = l_r[i] * scale + ps;
            m_r[i] = mn;
            acc[i][0] *= scale; acc[i][1] *= scale;
            acc[i][2] *= scale; acc[i][3] *= scale;
            PsT[tx*4+0][ty*4+i] = p0;
            PsT[tx*4+1][ty*4+i] = p1;
            PsT[tx*4+2][ty*4+i] = p2;
            PsT[tx*4+3][ty*4+i] = p3;
        }
        __syncthreads();
        #pragma unroll
        for (int jj = 0; jj < 64; ++jj) {    // acc += P @ V
            float pa[4], vv4[4];
            *(float4*)&pa[0]  = *(const float4*)&PsT[jj][ty*4];
            *(float4*)&vv4[0] = *(const float4*)&Vs[jj][tx*4];
            #pragma unroll
            for (int i = 0; i < 4; ++i)
                #pragma unroll
                for (int j = 0; j < 4; ++j)
                    acc[i][j] += pa[i] * vv4[j];
        }
    }

    const int b = bh >> 4, h = bh & 15;
    #pragma unroll
    for (int i = 0; i < 4; ++i) {            // ctx[b, s, h*64+dh] = acc / l
        const int q = q0 + ty*4 + i;
        const float inv = 1.0f / l_r[i];
        float4 r;
        r.x = acc[i][0]*inv; r.y = acc[i][1]*inv;
        r.z = acc[i][2]*inv; r.w = acc[i][3]*inv;
        *(float4*)&ctx[((size_t)(b*2048 + q))*1024 + (h<<6) + tx*4] = r;
    }
}

extern "C" void kernel_launch(void* const* d_in, const int* in_sizes, int n_in,
                              void* d_out, int out_size, void* d_ws, size_t ws_size,
                              hipStream_t stream)
{
    const float* queries = (const float*)d_in[0];
    const float* keys    = (const float*)d_in[1];
    const float* values  = (const float*)d_in[2];
    const int*   mask    = (const int*)  d_in[3];
    const float* Wq = (const float*)d_in[4];
    const float* bq = (const float*)d_in[5];
    const float* Wk = (const float*)d_in[6];
    const float* bk = (const float*)d_in[7];
    const float* Wv = (const float*)d_in[8];
    const float* bv = (const float*)d_in[9];
    const float* Wo = (const float*)d_in[10];
    const float* bo = (const float*)d_in[11];
    float* out = (float*)d_out;

    // workspace: 4 x 16 MiB fp32 buffers (needs 64 MiB)
    float* q2  = (float*)d_ws;
    float* kb  = q2 + (size_t)4*1024*1024;
    float* vb  = kb + (size_t)4*1024*1024;
    float* ctx = vb + (size_t)4*1024*1024;

    dim3 gblk(256);
    dim3 ggrid(8, 32);                       // N/128=8, M/128=32

    gemm_wt<2><<<ggrid, gblk, 0, stream>>>(queries, Wq, bq, q2);
    gemm_wt<1><<<ggrid, gblk, 0, stream>>>(keys,    Wk, bk, kb);
    gemm_wt<1><<<ggrid, gblk, 0, stream>>>(values,  Wv, bv, vb);
    attn_fwd<<<dim3(32, 32), dim3(256), 0, stream>>>(q2, kb, vb, mask, ctx);
    gemm_wt<0><<<ggrid, gblk, 0, stream>>>(ctx, Wo, bo, out);
}

// Round 2
// 244.688 us; speedup vs baseline: 5.2105x; 5.2105x over previous
//
#include <hip/hip_runtime.h>
#include <hip/hip_bf16.h>
#include <cstddef>
#include <cstdint>

// B=2, S=2048, D=1024, H=16, DH=64, M=B*S=4096
//
// Pipeline (all bf16 MFMA 16x16x32, fp32 accum):
//   convert x7: queries/keys/values/Wq/Wk/Wv/Wo -> bf16
//   qbuf = qin @ Wq^T + bq        (plain [4096][1024])
//   kbuf = kin @ Wk^T + bk        (plain [4096][1024])
//   vtb  = Wv @ vin^T + bv[row]   (= V^T, plain [1024][4096], swapped gemm)
//   ctx  = attn(qbuf,kbuf,vtb,mask)  (plain [4096][1024], head a reads q rows
//           s=((s2&127)*16+a), cols (s2>>7)*64.., per double-split_proj algebra)
//   out  = ctx @ Wo^T + bo        (fp32)

typedef __attribute__((ext_vector_type(8))) short bf16x8;
typedef __attribute__((ext_vector_type(4))) float f32x4;

__device__ __forceinline__ void gl_lds16(const void* g, void* l) {
    __builtin_amdgcn_global_load_lds(
        (const __attribute__((address_space(1))) void*)g,
        (__attribute__((address_space(3))) void*)l, 16, 0, 0);
}

// ---------------- fp32 -> bf16 convert, 8 elems/thread ----------------------
__global__ __launch_bounds__(256) void f2b8(const float* __restrict__ s,
                                            __hip_bfloat16* __restrict__ d, int n8)
{
    int i = blockIdx.x * 256 + threadIdx.x;
    if (i >= n8) return;
    const float4* sp = (const float4*)s + (size_t)i * 2;
    float4 v0 = sp[0], v1 = sp[1];
    union { __hip_bfloat16 h[8]; int4 q; } u;
    u.h[0] = __float2bfloat16(v0.x); u.h[1] = __float2bfloat16(v0.y);
    u.h[2] = __float2bfloat16(v0.z); u.h[3] = __float2bfloat16(v0.w);
    u.h[4] = __float2bfloat16(v1.x); u.h[5] = __float2bfloat16(v1.y);
    u.h[6] = __float2bfloat16(v1.z); u.h[7] = __float2bfloat16(v1.w);
    *((int4*)d + i) = u.q;
}

// ---------------- bf16 MFMA GEMM: D[i][j] = sum_k A[i,k]*Bm[j,k] (+bias) ----
// A: (M x 1024), Bm: (N x 1024), both row-major bf16. C: (M x N) row-major.
// grid = (N/128, M/128), 256 threads = 4 waves, m97 structure (BK=64).
template <int BIAS_ROW, typename OutT>
__global__ __launch_bounds__(256) void gemm_bt(
    const __hip_bfloat16* __restrict__ A,
    const __hip_bfloat16* __restrict__ Bm,
    const float* __restrict__ bias,
    OutT* __restrict__ C, int N)
{
    __shared__ __align__(16) __hip_bfloat16 As[128 * 64];
    __shared__ __align__(16) __hip_bfloat16 Bs[128 * 64];
    const int t = threadIdx.x, lane = t & 63, w = t >> 6;
    const int l15 = lane & 15, g = lane >> 4;
    const int m0 = blockIdx.y * 128, n0 = blockIdx.x * 128;
    const int wr = w >> 1, wc = w & 1;

    f32x4 acc[4][4] = {};

    for (int k0 = 0; k0 < 1024; k0 += 64) {
        __syncthreads();
        #pragma unroll
        for (int it = 0; it < 4; ++it) {
            const int chunk = it * 256 + w * 64 + lane;
            const int row = chunk >> 3, c = chunk & 7;
            gl_lds16(A  + (size_t)(m0 + row) * 1024 + k0 + c * 8, (char*)As + chunk * 16);
            gl_lds16(Bm + (size_t)(n0 + row) * 1024 + k0 + c * 8, (char*)Bs + chunk * 16);
        }
        __syncthreads();
        #pragma unroll
        for (int kk = 0; kk < 64; kk += 32) {
            bf16x8 af[4], bfr[4];
            #pragma unroll
            for (int i = 0; i < 4; ++i)
                af[i] = *(const bf16x8*)((const char*)As + (wr * 64 + i * 16 + l15) * 128 + kk * 2 + g * 16);
            #pragma unroll
            for (int j = 0; j < 4; ++j)
                bfr[j] = *(const bf16x8*)((const char*)Bs + (wc * 64 + j * 16 + l15) * 128 + kk * 2 + g * 16);
            #pragma unroll
            for (int i = 0; i < 4; ++i)
                #pragma unroll
                for (int j = 0; j < 4; ++j)
                    acc[i][j] = __builtin_amdgcn_mfma_f32_16x16x32_bf16(af[i], bfr[j], acc[i][j], 0, 0, 0);
        }
    }

    #pragma unroll
    for (int i = 0; i < 4; ++i) {
        const int m = m0 + wr * 64 + i * 16 + g * 4;   // +r below
        #pragma unroll
        for (int j = 0; j < 4; ++j) {
            const int n = n0 + wc * 64 + j * 16 + l15;
            const float bc = BIAS_ROW ? 0.f : bias[n];
            #pragma unroll
            for (int r = 0; r < 4; ++r) {
                const float v = acc[i][j][r] + (BIAS_ROW ? bias[m + r] : bc);
                C[(size_t)(m + r) * N + n] = (OutT)v;
            }
        }
    }
}

// ---------------- MFMA flash attention --------------------------------------
// grid = (32 q-tiles, 32 bh). Block: 4 waves; wave w owns q rows q0+w*16..+15.
// Softmax scale 1/8 folded into exp; mask applied as -8e9 on RAW scores.
__global__ __launch_bounds__(256) void attn_mfma(
    const __hip_bfloat16* __restrict__ qb,   // [4096][1024]
    const __hip_bfloat16* __restrict__ kb,   // [4096][1024]
    const __hip_bfloat16* __restrict__ vt,   // [1024][4096]  (V^T)
    const int* __restrict__ mask,            // [2048][2048]
    __hip_bfloat16* __restrict__ ctx)        // [4096][1024]
{
    __shared__ __align__(16) __hip_bfloat16 Qs[64 * 64];
    __shared__ __align__(16) __hip_bfloat16 Ks[64 * 64];
    __shared__ __align__(16) __hip_bfloat16 Vs[64 * 64];
    __shared__ __align__(16) __hip_bfloat16 Pb[4][16 * 64];
    const int t = threadIdx.x, lane = t & 63, w = t >> 6;
    const int l15 = lane & 15, g = lane >> 4;
    const int q0 = blockIdx.x * 64;
    const int bh = blockIdx.y, b = bh >> 4, a = bh & 15;
    const int hq = q0 >> 7;                  // original h for this q-tile

    // stage Q once (source XOR-swizzled by 16B chunk so frag reads are ~2-way)
    #pragma unroll
    for (int it = 0; it < 2; ++it) {
        const int chunk = w * 128 + it * 64 + lane;
        const int row = chunk >> 3, c = chunk & 7;
        const int cs = c ^ (row & 7);
        const int s = ((q0 & 127) + row) * 16 + a;   // inverse double-split
        gl_lds16(qb + (size_t)(b * 2048 + s) * 1024 + hq * 64 + cs * 8,
                 (char*)Qs + chunk * 16);
    }

    f32x4 accd[4] = {};
    float m_r[4], l_r[4];
    #pragma unroll
    for (int r = 0; r < 4; ++r) { m_r[r] = -1e30f; l_r[r] = 0.f; }

    const int qrow_lds = w * 16 + l15;       // A-operand row for QK^T

    for (int kt = 0; kt < 32; ++kt) {
        const int k0 = kt * 64;
        __syncthreads();                     // prev-iter reads done before overwrite
        #pragma unroll
        for (int it = 0; it < 2; ++it) {
            const int chunk = w * 128 + it * 64 + lane;
            const int row = chunk >> 3, c = chunk & 7;
            const int cs = c ^ (row & 7);
            gl_lds16(kb + (size_t)(b * 2048 + k0 + row) * 1024 + a * 64 + cs * 8,
                     (char*)Ks + chunk * 16);
            gl_lds16(vt + (size_t)(a * 64 + row) * 4096 + b * 2048 + k0 + cs * 8,
                     (char*)Vs + chunk * 16);
        }
        __syncthreads();                     // drains vmcnt (glds) per barrier semantics

        // ---- S = Q K^T (raw, unscaled) ----
        f32x4 sf[4] = {};
        #pragma unroll
        for (int kk8 = 0; kk8 < 8; kk8 += 4) {
            const int kc = kk8 + g;
            const bf16x8 aq = *(const bf16x8*)((const char*)Qs + qrow_lds * 128 + ((kc ^ (qrow_lds & 7)) * 16));
            #pragma unroll
            for (int nf = 0; nf < 4; ++nf) {
                const int krow = nf * 16 + l15;
                const bf16x8 bk = *(const bf16x8*)((const char*)Ks + krow * 128 + ((kc ^ (krow & 7)) * 16));
                sf[nf] = __builtin_amdgcn_mfma_f32_16x16x32_bf16(aq, bk, sf[nf], 0, 0, 0);
            }
        }

        // ---- mask + online softmax (lane owns q rows g*4+r of wave tile) ----
        #pragma unroll
        for (int r = 0; r < 4; ++r) {
            const int q = q0 + w * 16 + g * 4 + r;
            const size_t mrow = (size_t)q * 2048 + k0 + l15;
            float s0 = sf[0][r] + (float)mask[mrow]      * -8e9f;
            float s1 = sf[1][r] + (float)mask[mrow + 16] * -8e9f;
            float s2 = sf[2][r] + (float)mask[mrow + 32] * -8e9f;
            float s3 = sf[3][r] + (float)mask[mrow + 48] * -8e9f;
            float rm = fmaxf(fmaxf(s0, s1), fmaxf(s2, s3));
            rm = fmaxf(rm, __shfl_xor(rm, 1));
            rm = fmaxf(rm, __shfl_xor(rm, 2));
            rm = fmaxf(rm, __shfl_xor(rm, 4));
            rm = fmaxf(rm, __shfl_xor(rm, 8));
            const float mn = fmaxf(m_r[r], rm);
            const float scale = __expf((m_r[r] - mn) * 0.125f);
            const float p0 = __expf((s0 - mn) * 0.125f);
            const float p1 = __expf((s1 - mn) * 0.125f);
            const float p2 = __expf((s2 - mn) * 0.125f);
            const float p3 = __expf((s3 - mn) * 0.125f);
            float ps = p0 + p1 + p2 + p3;
            ps += __shfl_xor(ps, 1);
            ps += __shfl_xor(ps, 2);
            ps += __shfl_xor(ps, 4);
            ps += __shfl_xor(ps, 8);
            l_r[r] = l_r[r] * scale + ps;
            m_r[r] = mn;
            #pragma unroll
            for (int df = 0; df < 4; ++df) accd[df][r] *= scale;
            // transpose P into wave-private LDS (same 16B-chunk XOR swizzle)
            const int qrow = g * 4 + r;
            char* pbase = (char*)Pb[w] + qrow * 128;
            const int within = (l15 & 7) * 2, ch0 = l15 >> 3;
            *(__hip_bfloat16*)(pbase + ((0 + ch0) ^ (qrow & 7)) * 16 + within) = __float2bfloat16(p0);
            *(__hip_bfloat16*)(pbase + ((2 + ch0) ^ (qrow & 7)) * 16 + within) = __float2bfloat16(p1);
            *(__hip_bfloat16*)(pbase + ((4 + ch0) ^ (qrow & 7)) * 16 + within) = __float2bfloat16(p2);
            *(__hip_bfloat16*)(pbase + ((6 + ch0) ^ (qrow & 7)) * 16 + within) = __float2bfloat16(p3);
        }

        // ---- acc += P V (wave-private Pb: in-order wave LDS, no barrier) ----
        #pragma unroll
        for (int kk8 = 0; kk8 < 8; kk8 += 4) {
            const int kc = kk8 + g;
            const bf16x8 pa = *(const bf16x8*)((const char*)Pb[w] + l15 * 128 + ((kc ^ (l15 & 7)) * 16));
            #pragma unroll
            for (int df = 0; df < 4; ++df) {
                const int vrow = df * 16 + l15;
                const bf16x8 bv = *(const bf16x8*)((const char*)Vs + vrow * 128 + ((kc ^ (vrow & 7)) * 16));
                accd[df] = __builtin_amdgcn_mfma_f32_16x16x32_bf16(pa, bv, accd[df], 0, 0, 0);
            }
        }
    }

    #pragma unroll
    for (int r = 0; r < 4; ++r) {
        const int q = q0 + w * 16 + g * 4 + r;
        const float inv = 1.f / l_r[r];
        #pragma unroll
        for (int df = 0; df < 4; ++df)
            ctx[(size_t)(b * 2048 + q) * 1024 + a * 64 + df * 16 + l15] =
                __float2bfloat16(accd[df][r] * inv);
    }
}

extern "C" void kernel_launch(void* const* d_in, const int* in_sizes, int n_in,
                              void* d_out, int out_size, void* d_ws, size_t ws_size,
                              hipStream_t stream)
{
    const float* queries = (const float*)d_in[0];
    const float* keys    = (const float*)d_in[1];
    const float* values  = (const float*)d_in[2];
    const int*   mask    = (const int*)  d_in[3];
    const float* Wq = (const float*)d_in[4];
    const float* bq = (const float*)d_in[5];
    const float* Wk = (const float*)d_in[6];
    const float* bk = (const float*)d_in[7];
    const float* Wv = (const float*)d_in[8];
    const float* bv = (const float*)d_in[9];
    const float* Wo = (const float*)d_in[10];
    const float* bo = (const float*)d_in[11];

    const size_t NM = (size_t)4096 * 1024;   // 4,194,304
    const size_t NW = (size_t)1024 * 1024;
    __hip_bfloat16* p = (__hip_bfloat16*)d_ws;
    __hip_bfloat16* qin = p;  p += NM;
    __hip_bfloat16* kin = p;  p += NM;
    __hip_bfloat16* vin = p;  p += NM;
    __hip_bfloat16* Wqb = p;  p += NW;
    __hip_bfloat16* Wkb = p;  p += NW;
    __hip_bfloat16* Wvb = p;  p += NW;
    __hip_bfloat16* Wob = p;  p += NW;
    __hip_bfloat16* qbuf = p; p += NM;
    __hip_bfloat16* kbuf = p; p += NM;
    __hip_bfloat16* vtb  = p; p += NM;
    __hip_bfloat16* ctxb = qin;              // alias: qin dead after first gemm
    // total ws use: 6*NM + 4*NW bf16 = 58.7 MB (< 64 MiB)

    // converts
    f2b8<<<dim3(2048), dim3(256), 0, stream>>>(queries, qin, (int)(NM / 8));
    f2b8<<<dim3(2048), dim3(256), 0, stream>>>(keys,    kin, (int)(NM / 8));
    f2b8<<<dim3(2048), dim3(256), 0, stream>>>(values,  vin, (int)(NM / 8));
    f2b8<<<dim3(512),  dim3(256), 0, stream>>>(Wq, Wqb, (int)(NW / 8));
    f2b8<<<dim3(512),  dim3(256), 0, stream>>>(Wk, Wkb, (int)(NW / 8));
    f2b8<<<dim3(512),  dim3(256), 0, stream>>>(Wv, Wvb, (int)(NW / 8));
    f2b8<<<dim3(512),  dim3(256), 0, stream>>>(Wo, Wob, (int)(NW / 8));

    // projections
    gemm_bt<0, __hip_bfloat16><<<dim3(8, 32), dim3(256), 0, stream>>>(qin, Wqb, bq, qbuf, 1024);
    gemm_bt<0, __hip_bfloat16><<<dim3(8, 32), dim3(256), 0, stream>>>(kin, Wkb, bk, kbuf, 1024);
    gemm_bt<1, __hip_bfloat16><<<dim3(32, 8), dim3(256), 0, stream>>>(Wvb, vin, bv, vtb, 4096);

    // attention
    attn_mfma<<<dim3(32, 32), dim3(256), 0, stream>>>(qbuf, kbuf, vtb, mask, ctxb);

    // output projection (fp32 out)
    gemm_bt<0, float><<<dim3(8, 32), dim3(256), 0, stream>>>(ctxb, Wob, bo, (float*)d_out, 1024);
}

// Round 3
// 178.840 us; speedup vs baseline: 7.1290x; 1.3682x over previous
//
#include <hip/hip_runtime.h>
#include <hip/hip_bf16.h>
#include <cstddef>
#include <cstdint>

// B=2, S=2048, D=1024, H=16, DH=64, M=B*S=4096
//
// Pipeline (bf16 MFMA 16x16x32, fp32 accum):
//   convert_all: queries/keys/values/Wq/Wk/Wv/Wo -> bf16 (one kernel)
//   packmask:    mask int32 [2048][2048] -> bit-packed u64 [2048][32]
//   qkv_gemm:    qbuf = qin@Wq^T+bq, kbuf = kin@Wk^T+bk, vtb = Wv@vin^T+bv (V^T)
//   attn_mfma:   swapped QK^T (lane owns q-row), fixed-C softmax, PV
//   gemm_bt:     out = ctx @ Wo^T + bo (fp32 out)
//
// Double-split_proj algebra: head a of attention reads Q-projection rows
// s = (qrow&127)*16 + a with column block (q>>7)*64; K plain; V^T via swapped GEMM.

typedef __attribute__((ext_vector_type(8))) short bf16x8;
typedef __attribute__((ext_vector_type(4))) float f32x4;

__device__ __forceinline__ void gl_lds16(const void* g, void* l) {
    __builtin_amdgcn_global_load_lds(
        (const __attribute__((address_space(1))) void*)g,
        (__attribute__((address_space(3))) void*)l, 16, 0, 0);
}

// ---------------- all fp32->bf16 converts in one kernel ---------------------
__global__ __launch_bounds__(256) void convert_all(
    const float* __restrict__ q, const float* __restrict__ k, const float* __restrict__ v,
    const float* __restrict__ wq, const float* __restrict__ wk,
    const float* __restrict__ wv, const float* __restrict__ wo,
    __hip_bfloat16* __restrict__ dq, __hip_bfloat16* __restrict__ dk,
    __hip_bfloat16* __restrict__ dv, __hip_bfloat16* __restrict__ dwq,
    __hip_bfloat16* __restrict__ dwk, __hip_bfloat16* __restrict__ dwv,
    __hip_bfloat16* __restrict__ dwo)
{
    const int bid = blockIdx.x;
    const float* s; __hip_bfloat16* d; int base;
    if      (bid < 2048) { s = q;  d = dq;  base = bid; }
    else if (bid < 4096) { s = k;  d = dk;  base = bid - 2048; }
    else if (bid < 6144) { s = v;  d = dv;  base = bid - 4096; }
    else if (bid < 6656) { s = wq; d = dwq; base = bid - 6144; }
    else if (bid < 7168) { s = wk; d = dwk; base = bid - 6656; }
    else if (bid < 7680) { s = wv; d = dwv; base = bid - 7168; }
    else                 { s = wo; d = dwo; base = bid - 7680; }
    const size_t i = (size_t)base * 256 + threadIdx.x;
    const float4* sp = (const float4*)s + i * 2;
    float4 v0 = sp[0], v1 = sp[1];
    union { __hip_bfloat16 h[8]; int4 qd; } u;
    u.h[0] = __float2bfloat16(v0.x); u.h[1] = __float2bfloat16(v0.y);
    u.h[2] = __float2bfloat16(v0.z); u.h[3] = __float2bfloat16(v0.w);
    u.h[4] = __float2bfloat16(v1.x); u.h[5] = __float2bfloat16(v1.y);
    u.h[6] = __float2bfloat16(v1.z); u.h[7] = __float2bfloat16(v1.w);
    *((int4*)d + i) = u.qd;
}

// ---------------- mask -> bitmask: mbits[q][w] bit j = mask[q][w*64+j] ------
__global__ __launch_bounds__(256) void packmask(const int* __restrict__ mask,
                                                unsigned long long* __restrict__ mbits)
{
    const int wid  = (blockIdx.x * 256 + threadIdx.x) >> 6;  // 0..65535
    const int lane = threadIdx.x & 63;
    const int qr = wid >> 5, w64 = wid & 31;
    const int m = mask[(size_t)qr * 2048 + w64 * 64 + lane];
    const unsigned long long bal = __ballot(m != 0);
    if (lane == 0) mbits[(size_t)qr * 32 + w64] = bal;
}

// ---------------- shared GEMM body: C = A @ Bm^T (+bias), 128x128, BK=64 ---
template <typename OutT>
__device__ __forceinline__ void gemm_body(
    const __hip_bfloat16* __restrict__ A, const __hip_bfloat16* __restrict__ Bm,
    const float* __restrict__ bias, OutT* __restrict__ C,
    int N, int m0, int n0, int brow,
    __hip_bfloat16* As, __hip_bfloat16* Bs)
{
    const int t = threadIdx.x, lane = t & 63, w = t >> 6;
    const int l15 = lane & 15, g = lane >> 4;
    const int wr = w >> 1, wc = w & 1;

    f32x4 acc[4][4] = {};

    for (int k0 = 0; k0 < 1024; k0 += 64) {
        __syncthreads();
        #pragma unroll
        for (int it = 0; it < 4; ++it) {
            const int chunk = it * 256 + w * 64 + lane;
            const int row = chunk >> 3, c = chunk & 7;
            gl_lds16(A  + (size_t)(m0 + row) * 1024 + k0 + c * 8, (char*)As + chunk * 16);
            gl_lds16(Bm + (size_t)(n0 + row) * 1024 + k0 + c * 8, (char*)Bs + chunk * 16);
        }
        __syncthreads();
        #pragma unroll
        for (int kk = 0; kk < 64; kk += 32) {
            bf16x8 af[4], bfr[4];
            #pragma unroll
            for (int i = 0; i < 4; ++i)
                af[i] = *(const bf16x8*)((const char*)As + (wr * 64 + i * 16 + l15) * 128 + kk * 2 + g * 16);
            #pragma unroll
            for (int j = 0; j < 4; ++j)
                bfr[j] = *(const bf16x8*)((const char*)Bs + (wc * 64 + j * 16 + l15) * 128 + kk * 2 + g * 16);
            #pragma unroll
            for (int i = 0; i < 4; ++i)
                #pragma unroll
                for (int j = 0; j < 4; ++j)
                    acc[i][j] = __builtin_amdgcn_mfma_f32_16x16x32_bf16(af[i], bfr[j], acc[i][j], 0, 0, 0);
        }
    }

    #pragma unroll
    for (int i = 0; i < 4; ++i) {
        const int m = m0 + wr * 64 + i * 16 + g * 4;
        #pragma unroll
        for (int j = 0; j < 4; ++j) {
            const int n = n0 + wc * 64 + j * 16 + l15;
            const float bc = brow ? 0.f : bias[n];
            #pragma unroll
            for (int r = 0; r < 4; ++r) {
                const float v = acc[i][j][r] + (brow ? bias[m + r] : bc);
                C[(size_t)(m + r) * N + n] = (OutT)v;
            }
        }
    }
}

// fused Q/K/V projections: grid (8, 32, 3)
__global__ __launch_bounds__(256) void qkv_gemm(
    const __hip_bfloat16* __restrict__ qin, const __hip_bfloat16* __restrict__ kin,
    const __hip_bfloat16* __restrict__ vin,
    const __hip_bfloat16* __restrict__ Wqb, const __hip_bfloat16* __restrict__ Wkb,
    const __hip_bfloat16* __restrict__ Wvb,
    const float* __restrict__ bq, const float* __restrict__ bk, const float* __restrict__ bv,
    __hip_bfloat16* __restrict__ qbuf, __hip_bfloat16* __restrict__ kbuf,
    __hip_bfloat16* __restrict__ vtb)
{
    __shared__ __align__(16) __hip_bfloat16 As[128 * 64];
    __shared__ __align__(16) __hip_bfloat16 Bs[128 * 64];
    const int z = blockIdx.z;
    if (z == 0)
        gemm_body(qin, Wqb, bq, qbuf, 1024, blockIdx.y * 128, blockIdx.x * 128, 0, As, Bs);
    else if (z == 1)
        gemm_body(kin, Wkb, bk, kbuf, 1024, blockIdx.y * 128, blockIdx.x * 128, 0, As, Bs);
    else  // V^T = Wv @ vin^T, bias per output ROW (d)
        gemm_body(Wvb, vin, bv, vtb, 4096, blockIdx.x * 128, blockIdx.y * 128, 1, As, Bs);
}

// out projection (fp32 out): grid (8, 32)
__global__ __launch_bounds__(256) void out_gemm(
    const __hip_bfloat16* __restrict__ A, const __hip_bfloat16* __restrict__ Bm,
    const float* __restrict__ bias, float* __restrict__ C)
{
    __shared__ __align__(16) __hip_bfloat16 As[128 * 64];
    __shared__ __align__(16) __hip_bfloat16 Bs[128 * 64];
    gemm_body(A, Bm, bias, C, 1024, blockIdx.y * 128, blockIdx.x * 128, 0, As, Bs);
}

// ---------------- MFMA flash attention (swapped QK^T, fixed-C softmax) ------
// grid (16 q-tiles, 32 bh), 512 threads = 8 waves; wave w: q rows q0+w*16..+15.
// K/V double-buffered (T3 2-phase: stage next -> compute cur -> syncthreads).
__global__ __launch_bounds__(512) void attn_mfma(
    const __hip_bfloat16* __restrict__ qb,   // [4096][1024] plain Q projection
    const __hip_bfloat16* __restrict__ kb,   // [4096][1024] plain K projection
    const __hip_bfloat16* __restrict__ vt,   // [1024][4096] V^T
    const unsigned long long* __restrict__ mbits,  // [2048][32]
    __hip_bfloat16* __restrict__ ctx)        // [4096][1024]
{
    __shared__ __align__(16) __hip_bfloat16 Qs[128 * 64];      // 16 KB
    __shared__ __align__(16) __hip_bfloat16 Ks[2][64 * 64];    // 16 KB
    __shared__ __align__(16) __hip_bfloat16 Vs[2][64 * 64];    // 16 KB
    __shared__ __align__(16) __hip_bfloat16 Pb[8][16 * 64];    // 16 KB

    const int t = threadIdx.x, lane = t & 63, w = t >> 6;
    const int l15 = lane & 15, g = lane >> 4;
    const int q0 = blockIdx.x * 128;
    const int bh = blockIdx.y, b = bh >> 4, a = bh & 15;
    const int hq = blockIdx.x;               // q>>7 for this 128-row tile

    constexpr float SC_LOG2E = 0.18033688011112042f;   // 0.125*log2(e)
    constexpr float OFFC     = -17.312340490667561f;   // -12*log2(e)
    constexpr float MASKB    = -1.0e9f;

    // stage Q once: source row s = qrow*16 + a (inverse double-split), XOR-swz src
    #pragma unroll
    for (int it = 0; it < 2; ++it) {
        const int c = it * 512 + t;          // 0..1023
        const int row = c >> 3, cc = c & 7;
        const int cs = cc ^ (row & 7);
        const int s = row * 16 + a;
        gl_lds16(qb + (size_t)(b * 2048 + s) * 1024 + hq * 64 + cs * 8,
                 (char*)Qs + c * 16);
    }

    // stage K/V tile kt into buffer buf (1 chunk each per thread)
    auto stage_kv = [&](int buf, int kt) {
        const int c = t;                     // 0..511
        const int row = c >> 3, cc = c & 7;
        const int cs = cc ^ (row & 7);
        gl_lds16(kb + (size_t)(b * 2048 + kt * 64 + row) * 1024 + a * 64 + cs * 8,
                 (char*)Ks + buf * 8192 + c * 16);
        gl_lds16(vt + (size_t)(a * 64 + row) * 4096 + b * 2048 + kt * 64 + cs * 8,
                 (char*)Vs + buf * 8192 + c * 16);
    };

    stage_kv(0, 0);
    __syncthreads();                         // drains vmcnt: Q + tile0 ready

    f32x4 accd[4] = {};
    float l_r = 0.f;
    const int qrow = w * 16 + l15;           // wave-local q row (B operand)
    const int qg = q0 + qrow;                // attention row 0..2047

    for (int kt = 0; kt < 32; ++kt) {
        const int cur = kt & 1;
        if (kt < 31) stage_kv(cur ^ 1, kt + 1);   // prefetch next tile

        const uint2 mw = *(const uint2*)&mbits[(size_t)qg * 32 + kt];

        // ---- S^T = K Q^T : lane owns q-col l15, kk = 16nf+4g+r ----
        f32x4 sf[4] = {};
        #pragma unroll
        for (int half = 0; half < 2; ++half) {
            const int kc = half * 4 + g;
            const bf16x8 qf = *(const bf16x8*)((const char*)Qs + qrow * 128 + ((kc ^ (qrow & 7)) << 4));
            #pragma unroll
            for (int nf = 0; nf < 4; ++nf) {
                const int krow = nf * 16 + l15;
                const bf16x8 kf = *(const bf16x8*)((const char*)Ks + cur * 8192 + krow * 128 + ((kc ^ (krow & 7)) << 4));
                sf[nf] = __builtin_amdgcn_mfma_f32_16x16x32_bf16(kf, qf, sf[nf], 0, 0, 0);
            }
        }

        // ---- fixed-C softmax: p = exp2(s*0.125*log2e - 12*log2e), mask -> 0
        float psum = 0.f;
        #pragma unroll
        for (int nf = 0; nf < 4; ++nf) {
            const unsigned word = (nf & 2) ? mw.y : mw.x;
            const int bsh = ((nf & 1) << 4) + (g << 2);
            float pr[4];
            #pragma unroll
            for (int r = 0; r < 4; ++r) {
                const bool msk = (word >> (bsh + r)) & 1u;
                pr[r] = exp2f(fmaf(sf[nf][r], SC_LOG2E, msk ? MASKB : OFFC));
            }
            psum += (pr[0] + pr[1]) + (pr[2] + pr[3]);
            __hip_bfloat16 h0 = __float2bfloat16(pr[0]), h1 = __float2bfloat16(pr[1]);
            __hip_bfloat16 h2 = __float2bfloat16(pr[2]), h3 = __float2bfloat16(pr[3]);
            const unsigned w0 = (unsigned)*(unsigned short*)&h0 | ((unsigned)*(unsigned short*)&h1 << 16);
            const unsigned w1 = (unsigned)*(unsigned short*)&h2 | ((unsigned)*(unsigned short*)&h3 << 16);
            // P row q=l15 (wave-private), kk pair base 16nf+4g: byte 32nf+8g+{0,4}
            char* pb = (char*)Pb + w * 2048 + l15 * 128 +
                       (((2 * nf + (g >> 1)) ^ (l15 & 7)) << 4) + ((g & 1) << 3);
            *(uint2*)pb = make_uint2(w0, w1);
        }
        psum += __shfl_xor(psum, 16);
        psum += __shfl_xor(psum, 32);
        l_r += psum;

        // ---- acc += P V : A-frag = P row l15, kk chunk 8g.. (swz b128 read)
        #pragma unroll
        for (int jj = 0; jj < 2; ++jj) {
            const bf16x8 pa = *(const bf16x8*)((const char*)Pb + w * 2048 + l15 * 128 +
                                               (((4 * jj + g) ^ (l15 & 7)) << 4));
            #pragma unroll
            for (int df = 0; df < 4; ++df) {
                const int vrow = df * 16 + l15;
                const bf16x8 vf = *(const bf16x8*)((const char*)Vs + cur * 8192 + vrow * 128 +
                                                   (((4 * jj + g) ^ (vrow & 7)) << 4));
                accd[df] = __builtin_amdgcn_mfma_f32_16x16x32_bf16(pa, vf, accd[df], 0, 0, 0);
            }
        }

        __syncthreads();   // vmcnt(0)+barrier: prefetched tile ready, WAR safe
    }

    // epilogue: accd row m = g*4+r, col d = df*16+l15; l lives at lane (g*4+r)
    #pragma unroll
    for (int r = 0; r < 4; ++r) {
        const float lq = __shfl(l_r, (g << 2) + r);
        const float inv = 1.0f / lq;
        const int q = q0 + w * 16 + (g << 2) + r;
        #pragma unroll
        for (int df = 0; df < 4; ++df)
            ctx[(size_t)(b * 2048 + q) * 1024 + (a << 6) + df * 16 + l15] =
                __float2bfloat16(accd[df][r] * inv);
    }
}

extern "C" void kernel_launch(void* const* d_in, const int* in_sizes, int n_in,
                              void* d_out, int out_size, void* d_ws, size_t ws_size,
                              hipStream_t stream)
{
    const float* queries = (const float*)d_in[0];
    const float* keys    = (const float*)d_in[1];
    const float* values  = (const float*)d_in[2];
    const int*   mask    = (const int*)  d_in[3];
    const float* Wq = (const float*)d_in[4];
    const float* bq = (const float*)d_in[5];
    const float* Wk = (const float*)d_in[6];
    const float* bk = (const float*)d_in[7];
    const float* Wv = (const float*)d_in[8];
    const float* bv = (const float*)d_in[9];
    const float* Wo = (const float*)d_in[10];
    const float* bo = (const float*)d_in[11];

    const size_t NM = (size_t)4096 * 1024;
    const size_t NW = (size_t)1024 * 1024;
    __hip_bfloat16* p = (__hip_bfloat16*)d_ws;
    __hip_bfloat16* qin = p;  p += NM;
    __hip_bfloat16* kin = p;  p += NM;
    __hip_bfloat16* vin = p;  p += NM;
    __hip_bfloat16* Wqb = p;  p += NW;
    __hip_bfloat16* Wkb = p;  p += NW;
    __hip_bfloat16* Wvb = p;  p += NW;
    __hip_bfloat16* Wob = p;  p += NW;
    __hip_bfloat16* qbuf = p; p += NM;
    __hip_bfloat16* kbuf = p; p += NM;
    __hip_bfloat16* vtb  = p; p += NM;
    unsigned long long* mbits = (unsigned long long*)p;  // 512 KB
    __hip_bfloat16* ctxb = qin;              // alias: qin dead after qkv_gemm

    convert_all<<<dim3(8192), dim3(256), 0, stream>>>(
        queries, keys, values, Wq, Wk, Wv, Wo,
        qin, kin, vin, Wqb, Wkb, Wvb, Wob);
    packmask<<<dim3(16384), dim3(256), 0, stream>>>(mask, mbits);

    qkv_gemm<<<dim3(8, 32, 3), dim3(256), 0, stream>>>(
        qin, kin, vin, Wqb, Wkb, Wvb, bq, bk, bv, qbuf, kbuf, vtb);

    attn_mfma<<<dim3(16, 32), dim3(512), 0, stream>>>(qbuf, kbuf, vtb, mbits, ctxb);

    out_gemm<<<dim3(8, 32), dim3(256), 0, stream>>>(ctxb, Wob, bo, (float*)d_out);
}